// Round 10
// baseline (140.262 us; speedup 1.0000x reference)
//
#include <hip/hip_runtime.h>

// Part_CAM: only parts e=1..4 survive feat_cam[:,1:].
// Row-0-of-chain: e0^T * (sub[11] @ ... @ sub[0]) as 12 vec-mat products.
// Round 10: r9's fused 64-block design, with the streaming converted from
// 4x glds(size=4) (256B/request) to 1x glds(size=16) (1KB/request) per row.
// Hypothesis: per-CU streaming (measured ~13.5 GB/s) is outstanding-REQUEST
// limited, not bytes-limited; 4x bytes/request => ~4x per-CU BW.
// Alignment: rows start at arbitrary float offsets; stage the 16B-aligned
// window [rowbase-pad .. +255] (pad=(b+rr)&3) and shift reads by pad.
// Consume layout: lane owns cols {lane, 64+lane, 128+lane, 192+lane}
// (4x ds_read_b32, conflict-free). Epilogue fused into the same kernel:
// out[b,p,d] = sum_{g=5..200} vAll[g][p] * relu(F[g,d]) - one feat pass
// shared by all 4 parts.

#define L_ 12
#define B_ 64
#define N_ 201
#define D_ 768
#define NN_ ((size_t)N_ * N_)

#define RING 8
#define LEAD 6
#define RP 13            // rows per wave per layer (16 waves x 13 >= 201)
#define SLOT 272         // floats per slot: 256 data + overhang pad

// barrier that drains LDS ops but NOT vmcnt (prefetch survives)
#define BAR() asm volatile("s_waitcnt lgkmcnt(0)\n\ts_barrier" ::: "memory")
#define WAITC(n) asm volatile("s_waitcnt vmcnt(" #n ")" ::: "memory")

__device__ __forceinline__ void glds16(const float* g, float* l) {
    __builtin_amdgcn_global_load_lds(
        (const __attribute__((address_space(1))) void*)g,
        (__attribute__((address_space(3))) void*)l, 16, 0, 0);
}

__device__ __forceinline__ bool in_part(int p, int g) {
    const int e = p + 1;
    const int s = (p == 0) ? 5 : (p == 1) ? 5 : (p == 2) ? 54 : 103;
    const int t = (p == 0) ? 201 : (p == 1) ? 103 : (p == 2) ? 152 : 201;
    return (g == e) || (g >= s && g < t);
}

__global__ __launch_bounds__(1024) void part_cam_fused(
    const float* __restrict__ x,     // (L, B, N, N)
    const float* __restrict__ feat,  // (B, N, D)
    float* __restrict__ out)         // (B, 4, D)
{
    __shared__ __align__(16) float ring[16 * RING * SLOT]; // 136 KB
    __shared__ __align__(16) float vAll[256 * 4];          // [g][p], 4 KB
    __shared__ __align__(16) float red[16 * 256];          // 16 KB

    const int b    = blockIdx.x;
    const int tid  = threadIdx.x;
    const int lane = tid & 63;
    const int w    = tid >> 6;       // wave 0..15 (row group)

    // one glds16 stages the aligned 256-float window of row rr into slot isl:
    // slot float f  <=>  global float (rowbase - pad + f), pad=(b+rr)&3.
    auto ISSUE = [&](const float* xl, int j, int isl) {
        int rr = 1 + w * RP + j;
        if (rr > 200) rr = 0;        // clamped rows: v[0]==0, data unused
        const int pad = (b + rr) & 3;
        const float* srow = xl + (size_t)rr * N_ - pad;   // 16B-aligned
        float* sb = ring + (size_t)(w * RING + isl) * SLOT;
        glds16(srow + 4 * lane, sb); // lane's 16B -> LDS base + lane*16
    };

    // init loads (retire before loop via compiler wait), then prologue issues
    float iv0 = 0.f, iv1 = 0.f, iv2 = 0.f, iv3 = 0.f;
    if (tid < 256) {
        const float* x11 = x + ((size_t)11 * B_ + b) * NN_;
        const int g = (tid <= 200) ? tid : 200;
        iv0 = x11[(size_t)1 * N_ + g];
        iv1 = x11[(size_t)2 * N_ + g];
        iv2 = x11[(size_t)3 * N_ + g];
        iv3 = x11[(size_t)4 * N_ + g];
    }

    const float* xli = x + ((size_t)10 * B_ + b) * NN_;
    #pragma unroll
    for (int g0 = 0; g0 < LEAD; ++g0) ISSUE(xli, g0, g0);
    int ji = LEAD, sl = 0;

    if (tid < 256) {
        vAll[tid * 4 + 0] = in_part(0, tid) ? iv0 : 0.f;
        vAll[tid * 4 + 1] = in_part(1, tid) ? iv1 : 0.f;
        vAll[tid * 4 + 2] = in_part(2, tid) ? iv2 : 0.f;
        vAll[tid * 4 + 3] = in_part(3, tid) ? iv3 : 0.f;
    }
    BAR();

    // acc layout: component i of accP = partial for col (i*64 + lane), part P
    float4 acc0 = {0,0,0,0}, acc1 = {0,0,0,0}, acc2 = {0,0,0,0}, acc3 = {0,0,0,0};

    auto CONSUME = [&](int j) {
        int rr = 1 + w * RP + j;
        if (rr > 200) rr = 0;
        const int pad = (b + rr) & 3;
        const float* sp = ring + (size_t)(w * RING + sl) * SLOT + pad + lane;
        float x0 = sp[0], x1 = sp[64], x2 = sp[128], x3 = sp[192];
        float4 vv = *(const float4*)(vAll + rr * 4);   // broadcast
        acc0.x += vv.x * x0; acc0.y += vv.x * x1; acc0.z += vv.x * x2; acc0.w += vv.x * x3;
        acc1.x += vv.y * x0; acc1.y += vv.y * x1; acc1.z += vv.y * x2; acc1.w += vv.y * x3;
        acc2.x += vv.z * x0; acc2.y += vv.z * x1; acc2.z += vv.z * x2; acc2.w += vv.z * x3;
        acc3.x += vv.w * x0; acc3.y += vv.w * x1; acc3.z += vv.w * x2; acc3.w += vv.w * x3;
    };

    auto REDUCE = [&]() {
        #pragma unroll
        for (int pp = 0; pp < 4; ++pp) {
            float4 a = (pp == 0) ? acc0 : (pp == 1) ? acc1 : (pp == 2) ? acc2 : acc3;
            red[(w << 8) +   0 + lane] = a.x;   // col  0+lane
            red[(w << 8) +  64 + lane] = a.y;   // col 64+lane
            red[(w << 8) + 128 + lane] = a.z;
            red[(w << 8) + 192 + lane] = a.w;
            BAR();
            if (tid < 256) {
                float sum = 0.f;
                #pragma unroll
                for (int ww = 0; ww < 16; ++ww) sum += red[(ww << 8) + tid];
                vAll[tid * 4 + pp] = in_part(pp, tid) ? sum : 0.f;
            }
            BAR();
        }
        acc0 = make_float4(0,0,0,0); acc1 = make_float4(0,0,0,0);
        acc2 = make_float4(0,0,0,0); acc3 = make_float4(0,0,0,0);
    };

    for (int l = 10; l >= 1; --l) {
        #pragma unroll
        for (int j = 0; j < RP; ++j) {
            WAITC(5);                // 6 slot-requests in flight; oldest landed
            CONSUME(j);
            int isl = sl + LEAD; if (isl >= RING) isl -= RING;
            ISSUE(xli, ji, isl);     // writes slot consumed 2 iterations ago
            ji++;
            if (ji == RP) { ji = 0; xli -= (size_t)B_ * NN_; }
            sl = (sl + 1 == RING) ? 0 : sl + 1;
        }
        REDUCE();
    }
    // layer 0: issues stop, drain once
    #pragma unroll
    for (int j = 0; j < RP; ++j) {
        if (j < RP - LEAD) { WAITC(5); }
        else if (j == RP - LEAD) { WAITC(0); }
        CONSUME(j);
        if (j < RP - LEAD) {
            int isl = sl + LEAD; if (isl >= RING) isl -= RING;
            ISSUE(xli, ji, isl);
            ji++;
        }
        sl = (sl + 1 == RING) ? 0 : sl + 1;
    }
    REDUCE();

    // fused epilogue: out[b,p,d] = sum_{g=5..200} vAll[g][p] * relu(F[g,d]).
    // vAll is zero outside each part's [s_p,t_p) and e_p<5, so one masked
    // pass over feat[b] serves all 4 parts.
    if (tid < D_) {
        const float* fb = feat + (size_t)b * N_ * D_ + tid;
        float e0 = 0.f, e1 = 0.f, e2 = 0.f, e3 = 0.f;
        for (int g = 5; g < 201; g += 8) {
            float f[8];
            #pragma unroll
            for (int q = 0; q < 8; ++q)
                if (g + q < 201) f[q] = fb[(size_t)(g + q) * D_];
            #pragma unroll
            for (int q = 0; q < 8; ++q) {
                if (g + q < 201) {
                    float4 vv = *(const float4*)(vAll + (g + q) * 4);
                    float r = fmaxf(f[q], 0.f);
                    e0 += vv.x * r; e1 += vv.y * r; e2 += vv.z * r; e3 += vv.w * r;
                }
            }
        }
        float* ob = out + (size_t)b * 4 * D_ + tid;
        ob[0]      = e0;
        ob[D_]     = e1;
        ob[2 * D_] = e2;
        ob[3 * D_] = e3;
    }
}

extern "C" void kernel_launch(void* const* d_in, const int* in_sizes, int n_in,
                              void* d_out, int out_size, void* d_ws, size_t ws_size,
                              hipStream_t stream) {
    const float* x    = (const float*)d_in[0];
    const float* feat = (const float*)d_in[1];
    float* out = (float*)d_out;
    part_cam_fused<<<dim3(64), dim3(1024), 0, stream>>>(x, feat, out);
}